// Round 4
// baseline (1413.595 us; speedup 1.0000x reference)
//
#include <hip/hip_runtime.h>
#include <stdint.h>

#define K_DIM 4096
#define N_DIM 11008
#define M_DIM 8192
#define BM 256
#define BN 256
#define BK 64
#define NSLAB (K_DIM / BK)   // 64
#define ABUF (BM * BK)       // 16384 halves = 32 KiB per buffer
#define BBUF (BN * BK)
#define NBN (N_DIM / BN)     // 43
#define NWG (NBN * (M_DIM / BM))   // 1376, % 8 == 0

// fallback (round-0 validated) kernel params
#define FBM 128
#define FBK 32
#define FASTRIDE 32
#define FBSTRIDE 40

typedef _Float16 half8  __attribute__((ext_vector_type(8)));
typedef _Float16 half2v __attribute__((ext_vector_type(2)));
typedef float    floatx4 __attribute__((ext_vector_type(4)));

#define WS_NEEDED ((size_t)M_DIM * K_DIM * 2)   // 64 MiB: fp16 copy of x

__device__ __forceinline__ void async_lds16(const void* g, void* l) {
    __builtin_amdgcn_global_load_lds(
        (const __attribute__((address_space(1))) uint32_t*)g,
        (__attribute__((address_space(3))) uint32_t*)l, 16, 0, 0);
}

// ---------------- prepass: x fp32 -> fp16 (lossless; values are fp16-representable) ----
__global__ __launch_bounds__(256) void cvt_a(const float* __restrict__ x,
                                             _Float16* __restrict__ xh) {
    const size_t i = ((size_t)blockIdx.x * 256 + threadIdx.x) * 8;
    const float4 a = *(const float4*)(x + i);
    const float4 b = *(const float4*)(x + i + 4);
    half8 h;
    h[0] = (_Float16)a.x; h[1] = (_Float16)a.y; h[2] = (_Float16)a.z; h[3] = (_Float16)a.w;
    h[4] = (_Float16)b.x; h[5] = (_Float16)b.y; h[6] = (_Float16)b.z; h[7] = (_Float16)b.w;
    *(half8*)(xh + i) = h;
}

// ---------------- main GEMM: 256x256, 8-wave (2Mx4N), dbuf, 4 fine phases per K-tile ----
// Phase p: { ds_read subtile || stage-issue || s_barrier || setprio(1) 16xMFMA setprio(0)
//            || s_barrier }.  Publish barrier (ph3) waits vmcnt(2)+lgkm(0) only: next
//            tile's B-prefetch dwords stay in flight; vmcnt never drains to 0 in steady
//            state (T3/T4).  XOR chunk-swizzle on A (pre-swizzled DMA src) and B
//            (swizzled ds_write) -- proven conflict-free in round 3 (counter = 0).
__global__ __launch_bounds__(512, 2) void ternary_gemm_8p(
    const _Float16* __restrict__ xh,   // (M, K) fp16
    const int*   __restrict__ pw,      // (K/16, N) packed 2-bit codes
    const float* __restrict__ scales,  // (K/128, N) fp32 holding fp16 values
    const float* __restrict__ bias,    // (N,) fp32 holding fp16 values
    float*       __restrict__ out)     // (M, N) fp32
{
    __shared__ __align__(16) _Float16 lds_a[2 * ABUF];  // 64 KiB
    __shared__ __align__(16) _Float16 lds_b[2 * BBUF];  // 64 KiB

    const int tid  = threadIdx.x;
    const int lane = tid & 63;
    const int w    = tid >> 6;

    // XCD-aware bijective swizzle (NWG % 8 == 0)
    const int bid = blockIdx.x;
    const int swz = (bid & 7) * (NWG / 8) + (bid >> 3);
    const int n0 = (swz % NBN) * BN;
    const int m0 = (swz / NBN) * BM;

    const int wm = (w >> 2) * 128;   // wave tile: 128 (m) x 64 (n)
    const int wn = (w & 3) * 64;

    // ---- A staging: 4 gload_lds/thread/tile, linear LDS dest, pre-swizzled source ----
    const _Float16* gaS[4];
    int laOff[4];
    #pragma unroll
    for (int r = 0; r < 4; ++r) {
        const int idx = tid + r * 512;          // 0..2047
        const int row = idx >> 3;               // 0..255
        const int c   = idx & 7;                // 16B chunk
        gaS[r]   = xh + (size_t)(m0 + row) * K_DIM + ((c ^ (row & 7)) * 8);
        laOff[r] = idx * 8;                     // halves (byte = idx*16)
    }

    // ---- B staging: thread = (col nb, dword-pair kp); 2 dwords -> 4 swizzled b128 ----
    const int nb = tid >> 1;                    // 0..255
    const int kp = tid & 1;                     // dwords kp*2, kp*2+1 of the tile
    const int* pwp = pw + (size_t)(kp * 2) * N_DIM + n0 + nb;
    const float* scp = scales + n0 + nb;
    const int s7  = nb & 7;
    const int c0a = ((kp * 2 + 0) * 2 + 0) ^ s7;
    const int c0b = ((kp * 2 + 0) * 2 + 1) ^ s7;
    const int c1a = ((kp * 2 + 1) * 2 + 0) ^ s7;
    const int c1b = ((kp * 2 + 1) * 2 + 1) ^ s7;
    const int blOff = nb * BK;

    floatx4 acc[8][4];
    #pragma unroll
    for (int i = 0; i < 8; ++i)
        #pragma unroll
        for (int j = 0; j < 4; ++j)
            acc[i][j] = floatx4{0.f, 0.f, 0.f, 0.f};

    const int lr = lane & 15;
    const int g  = lane >> 4;
    const int x7 = lr & 7;

    auto permq = [](uint32_t v, uint32_t tmpl, uint32_t* q) {
        #pragma unroll
        for (int j = 0; j < 8; ++j) {
            uint32_t t4 = (v >> (4 * j)) & 0xFu;
            uint32_t sp = (t4 | (t4 << 14)) & 0x00030003u;
            uint32_t sel = ((sp & 0x00010001u) << 1) | ((0x00030003u - sp) << 8);
            q[j] = __builtin_amdgcn_perm(tmpl, tmpl, sel);
        }
    };
    auto stage_b = [&](uint32_t v0, uint32_t v1, float scf, int buf) {
        _Float16* rowb = lds_b + buf * BBUF + blOff;
        _Float16 sh = (_Float16)scf;           // lossless (value is fp16)
        uint32_t sbits = (uint32_t)__builtin_bit_cast(unsigned short, sh);
        uint32_t tmpl = sbits | (((sbits >> 8) ^ 0x80u) << 24);
        uint32_t q[8];
        permq(v0, tmpl, q);
        *(uint4*)(rowb + c0a * 8) = make_uint4(q[0], q[1], q[2], q[3]);
        *(uint4*)(rowb + c0b * 8) = make_uint4(q[4], q[5], q[6], q[7]);
        permq(v1, tmpl, q);
        *(uint4*)(rowb + c1a * 8) = make_uint4(q[0], q[1], q[2], q[3]);
        *(uint4*)(rowb + c1b * 8) = make_uint4(q[4], q[5], q[6], q[7]);
    };
    auto stage_a_h = [&](int t, int buf, int h) {      // rounds 2h, 2h+1
        #pragma unroll
        for (int r = 2 * h; r < 2 * h + 2; ++r)
            async_lds16(gaS[r] + t * BK, lds_a + buf * ABUF + laOff[r]);
    };
    auto ldA = [&](const _Float16* Ab, int q, half8* af) {
        #pragma unroll
        for (int mt = 0; mt < 4; ++mt)
            #pragma unroll
            for (int ks = 0; ks < 2; ++ks)
                af[mt * 2 + ks] = *(const half8*)
                    &Ab[(wm + q * 64 + mt * 16 + lr) * BK + (((ks * 4 + g) ^ x7) * 8)];
    };
    auto ldB = [&](const _Float16* Bb, int rr, half8* bf) {
        #pragma unroll
        for (int nt = 0; nt < 2; ++nt)
            #pragma unroll
            for (int ks = 0; ks < 2; ++ks)
                bf[nt * 2 + ks] = *(const half8*)
                    &Bb[(wn + rr * 32 + nt * 16 + lr) * BK + (((ks * 4 + g) ^ x7) * 8)];
    };
    auto MM = [&](int q, int rr, const half8* af, const half8* bf) {
        __builtin_amdgcn_s_setprio(1);
        #pragma unroll
        for (int ks = 0; ks < 2; ++ks)
            #pragma unroll
            for (int mt = 0; mt < 4; ++mt)
                #pragma unroll
                for (int nt = 0; nt < 2; ++nt)
                    acc[q * 4 + mt][rr * 2 + nt] = __builtin_amdgcn_mfma_f32_16x16x32_f16(
                        af[mt * 2 + ks], bf[nt * 2 + ks], acc[q * 4 + mt][rr * 2 + nt], 0, 0, 0);
        __builtin_amdgcn_s_setprio(0);
    };

    // ---- prologue: stage tile 0 fully, prefetch tile-1 B dwords, full drain once ----
    {
        uint32_t p0 = (uint32_t)pwp[0];
        uint32_t p1 = (uint32_t)pwp[(size_t)1 * N_DIM];
        float s0 = scp[0];
        stage_a_h(0, 0, 0); stage_a_h(0, 0, 1);
        stage_b(p0, p1, s0, 0);
    }
    uint32_t pvA0 = (uint32_t)pwp[(size_t)4 * N_DIM];
    uint32_t pvA1 = (uint32_t)pwp[(size_t)5 * N_DIM];
    float    scA  = scp[0];                       // group of tile 1 == 0
    asm volatile("s_waitcnt vmcnt(0) lgkmcnt(0)" ::: "memory");
    __builtin_amdgcn_s_barrier();

    uint32_t pvB0 = 0, pvB1 = 0; float scB = 0.f;

    for (int t = 0; t < NSLAB; ++t) {
        const int cur = t & 1;
        const _Float16* Ab = lds_a + cur * ABUF;
        const _Float16* Bb = lds_b + cur * BBUF;
        const bool stg  = (t + 1 < NSLAB);
        const bool pref = (t + 2 < NSLAB);

        half8 af[8], bf0[4], bf1[4];

        // ---- ph0: A(q0)+B(r0) reads | A-DMA rounds 0-1 | MFMA (q0,r0) ----
        ldA(Ab, 0, af);
        ldB(Bb, 0, bf0);
        if (stg) stage_a_h(t + 1, cur ^ 1, 0);
        __builtin_amdgcn_s_barrier();
        MM(0, 0, af, bf0);
        __builtin_amdgcn_s_barrier();

        // ---- ph1: B(r1) reads | A-DMA rounds 2-3 | MFMA (q0,r1) ----
        ldB(Bb, 1, bf1);
        if (stg) stage_a_h(t + 1, cur ^ 1, 1);
        __builtin_amdgcn_s_barrier();
        MM(0, 1, af, bf1);
        __builtin_amdgcn_s_barrier();

        // ---- ph2: A(q1) reads | B-dword prefetch (t+2) | MFMA (q1,r1) ----
        ldA(Ab, 1, af);
        if (pref) {
            pvB0 = (uint32_t)pwp[(size_t)((t + 2) * 4 + 0) * N_DIM];
            pvB1 = (uint32_t)pwp[(size_t)((t + 2) * 4 + 1) * N_DIM];
            scB  = scp[(size_t)((t + 2) >> 1) * N_DIM];
        }
        __builtin_amdgcn_s_barrier();
        MM(1, 1, af, bf1);
        __builtin_amdgcn_s_barrier();

        // ---- ph3: B dequant+writes (t+1) | publish (vmcnt counted) | MFMA (q1,r0) ----
        if (stg) {
            stage_b(pvA0, pvA1, scA, cur ^ 1);
            if (pref) asm volatile("s_waitcnt vmcnt(2)" ::: "memory");  // A-DMA(t+1) done;
            else      asm volatile("s_waitcnt vmcnt(0)" ::: "memory");  // pv stays in flight
            asm volatile("s_waitcnt lgkmcnt(0)" ::: "memory");          // B writes drained
        }
        __builtin_amdgcn_s_barrier();          // publish buffer t+1
        MM(1, 0, af, bf0);
        __builtin_amdgcn_s_barrier();

        pvA0 = pvB0; pvA1 = pvB1; scA = scB;
    }

    // ---- epilogue: fp32 acc + fp32 bias, stored unrounded (validated numerics) ----
    float bv[4];
    #pragma unroll
    for (int nt = 0; nt < 4; ++nt) bv[nt] = bias[n0 + wn + nt * 16 + lr];

    const int rbase = g * 4;          // C layout: row = (lane>>4)*4 + reg
    #pragma unroll
    for (int i = 0; i < 8; ++i) {
        #pragma unroll
        for (int j = 0; j < 4; ++j) {
            const int col = n0 + wn + j * 16 + lr;
            float* op = out + (size_t)(m0 + wm + i * 16 + rbase) * N_DIM + col;
            floatx4 a = acc[i][j];
            #pragma unroll
            for (int r = 0; r < 4; ++r)
                op[(size_t)r * N_DIM] = a[r] + bv[j];
        }
    }
}

// ---------------- fallback: round-0 validated kernel (used if ws too small) ------------
__global__ __launch_bounds__(256, 2) void ternary_gemm(
    const float* __restrict__ x,
    const int*   __restrict__ pw,
    const float* __restrict__ scales,
    const float* __restrict__ bias,
    float*       __restrict__ out)
{
    __shared__ __align__(16) _Float16 lds_a[FBM * FASTRIDE];
    __shared__ __align__(16) _Float16 lds_b[FBM * FBSTRIDE];

    const int tid  = threadIdx.x;
    const int lane = tid & 63;
    const int wave = tid >> 6;

    const int n0 = blockIdx.x * FBM;
    const int m0 = blockIdx.y * FBM;

    const int wm = (wave & 1) * 64;
    const int wn = (wave >> 1) * 64;

    const int nb  = tid & 127;
    const int kpi = tid >> 7;
    const int*   pwp = pw + (size_t)kpi * N_DIM + n0 + nb;
    const float* scp = scales + n0 + nb;
    _Float16* bl = lds_b + nb * FBSTRIDE + kpi * 16;

    floatx4 acc[4][4];
    #pragma unroll
    for (int i = 0; i < 4; ++i)
        #pragma unroll
        for (int j = 0; j < 4; ++j)
            acc[i][j] = floatx4{0.f, 0.f, 0.f, 0.f};

    const int lr = lane & 15;
    const int qk = (lane >> 4) * 8;

    for (int slab = 0; slab < K_DIM / FBK; ++slab) {
        const int k0 = slab * FBK;

        #pragma unroll
        for (int i = 0; i < 4; ++i) {
            const int idx = tid + i * 256;
            const int row = idx >> 3;
            const int kq  = (idx & 7) * 4;
            float4 v4 = *(const float4*)(x + (size_t)(m0 + row) * K_DIM + k0 + kq);
            half2v h0; h0[0] = (_Float16)v4.x; h0[1] = (_Float16)v4.y;
            half2v h1; h1[0] = (_Float16)v4.z; h1[1] = (_Float16)v4.w;
            *(uint2*)(lds_a + row * FASTRIDE + kq) =
                make_uint2(__builtin_bit_cast(uint32_t, h0),
                           __builtin_bit_cast(uint32_t, h1));
        }

        uint32_t v  = (uint32_t)pwp[(size_t)slab * 2 * N_DIM];
        _Float16 sh = (_Float16)scp[(size_t)(slab >> 2) * N_DIM];
        uint32_t sbits = (uint32_t)__builtin_bit_cast(unsigned short, sh);
        uint32_t tmpl = sbits | (((sbits >> 8) ^ 0x80u) << 24);

        uint32_t q[8];
        #pragma unroll
        for (int j = 0; j < 8; ++j) {
            uint32_t t4 = (v >> (4 * j)) & 0xFu;
            uint32_t sp = (t4 | (t4 << 14)) & 0x00030003u;
            uint32_t sel = ((sp & 0x00010001u) << 1) | ((0x00030003u - sp) << 8);
            q[j] = __builtin_amdgcn_perm(tmpl, tmpl, sel);
        }
        *(uint4*)(bl)     = make_uint4(q[0], q[1], q[2], q[3]);
        *(uint4*)(bl + 8) = make_uint4(q[4], q[5], q[6], q[7]);

        __syncthreads();

        half8 af[4], bfr[4];
        #pragma unroll
        for (int t = 0; t < 4; ++t) {
            af[t]  = *(const half8*)&lds_a[(wm + t * 16 + lr) * FASTRIDE + qk];
            bfr[t] = *(const half8*)&lds_b[(wn + t * 16 + lr) * FBSTRIDE + qk];
        }
        #pragma unroll
        for (int mt = 0; mt < 4; ++mt)
            #pragma unroll
            for (int nt = 0; nt < 4; ++nt)
                acc[mt][nt] = __builtin_amdgcn_mfma_f32_16x16x32_f16(
                    af[mt], bfr[nt], acc[mt][nt], 0, 0, 0);

        __syncthreads();
    }

    float bv[4];
    #pragma unroll
    for (int nt = 0; nt < 4; ++nt) bv[nt] = bias[n0 + wn + nt * 16 + lr];

    const int rbase = (lane >> 4) * 4;
    #pragma unroll
    for (int mt = 0; mt < 4; ++mt) {
        #pragma unroll
        for (int nt = 0; nt < 4; ++nt) {
            const int col = n0 + wn + nt * 16 + lr;
            float* op = out + (size_t)(m0 + wm + mt * 16 + rbase) * N_DIM + col;
            floatx4 a = acc[mt][nt];
            #pragma unroll
            for (int r = 0; r < 4; ++r)
                op[(size_t)r * N_DIM] = a[r] + bv[nt];
        }
    }
}

extern "C" void kernel_launch(void* const* d_in, const int* in_sizes, int n_in,
                              void* d_out, int out_size, void* d_ws, size_t ws_size,
                              hipStream_t stream) {
    const float* x  = (const float*)d_in[0];
    const int*   pw = (const int*)d_in[1];
    const float* sc = (const float*)d_in[2];
    const float* bs = (const float*)d_in[3];
    float* out = (float*)d_out;

    if (d_ws != nullptr && ws_size >= WS_NEEDED) {
        _Float16* xh = (_Float16*)d_ws;
        cvt_a<<<dim3((unsigned)((size_t)M_DIM * K_DIM / (256 * 8))), 256, 0, stream>>>(x, xh);
        ternary_gemm_8p<<<dim3(NWG), 512, 0, stream>>>(xh, pw, sc, bs, out);
    } else {
        ternary_gemm<<<dim3(N_DIM / FBM, M_DIM / FBM), 256, 0, stream>>>(x, pw, sc, bs, out);
    }
}

// Round 5
// 1182.644 us; speedup vs baseline: 1.1953x; 1.1953x over previous
//
#include <hip/hip_runtime.h>
#include <stdint.h>

#define K_DIM 4096
#define N_DIM 11008
#define M_DIM 8192
#define BM 256
#define BN 128
#define BK 64
#define NSLAB (K_DIM / BK)   // 64
#define NBN (N_DIM / BN)     // 86
#define NBM (M_DIM / BM)     // 32
#define NWG (NBN * NBM)      // 2752, % 8 == 0; /8 = 344 = 4 m-panels x 86

// fallback (round-0 validated) kernel params
#define FBM 128
#define FBK 32
#define FASTRIDE 32
#define FBSTRIDE 40

typedef _Float16 half8   __attribute__((ext_vector_type(8)));
typedef _Float16 half2v  __attribute__((ext_vector_type(2)));
typedef float    floatx4 __attribute__((ext_vector_type(4)));
typedef float    floatx16 __attribute__((ext_vector_type(16)));

#define WS_NEEDED ((size_t)M_DIM * K_DIM * 2)   // 64 MiB: fp16 copy of x

__device__ __forceinline__ void async_lds16(const void* g, void* l) {
    __builtin_amdgcn_global_load_lds(
        (const __attribute__((address_space(1))) uint32_t*)g,
        (__attribute__((address_space(3))) uint32_t*)l, 16, 0, 0);
}

// ---------------- prepass: x fp32 -> fp16 (lossless; values are fp16-representable) ----
__global__ __launch_bounds__(256) void cvt_a(const float* __restrict__ x,
                                             _Float16* __restrict__ xh) {
    const size_t i = ((size_t)blockIdx.x * 256 + threadIdx.x) * 8;
    const float4 a = *(const float4*)(x + i);
    const float4 b = *(const float4*)(x + i + 4);
    half8 h;
    h[0] = (_Float16)a.x; h[1] = (_Float16)a.y; h[2] = (_Float16)a.z; h[3] = (_Float16)a.w;
    h[4] = (_Float16)b.x; h[5] = (_Float16)b.y; h[6] = (_Float16)b.z; h[7] = (_Float16)b.w;
    *(half8*)(xh + i) = h;
}

// ---------------- main GEMM: round-2 structure (2-barrier, 2 blocks/CU) +
//   (1) B packed-dword/scale prefetch one slab ahead (hides B-load latency)
//   (2) XCD-aware m-panel-major block swizzle (A panel L2-resident per XCD)
//   (3) 32x32x16 f16 MFMA, XOR chunk-swizzle on BOTH A (pre-swizzled DMA src)
//       and B (swizzled ds_write) -- conflict-free pattern proven in r3/r4 ----------------
__global__ __launch_bounds__(512, 4) void ternary_gemm_w3(
    const _Float16* __restrict__ xh,   // (M, K) fp16
    const int*   __restrict__ pw,      // (K/16, N) packed 2-bit codes
    const float* __restrict__ scales,  // (K/128, N) fp32 holding fp16 values
    const float* __restrict__ bias,    // (N,) fp32 holding fp16 values
    float*       __restrict__ out)     // (M, N) fp32
{
    __shared__ __align__(16) _Float16 lds_a[BM * BK];   // 32 KiB, linear dest (DMA)
    __shared__ __align__(16) _Float16 lds_b[BN * BK];   // 16 KiB, XOR-swizzled content

    const int tid  = threadIdx.x;
    const int lane = tid & 63;
    const int w    = tid >> 6;

    // XCD-aware bijective swizzle; m-panel-major within an XCD chunk of 344
    const int bid = blockIdx.x;
    const int swz = (bid & 7) * (NWG / 8) + (bid >> 3);
    const int m0 = (swz / NBN) * BM;
    const int n0 = (swz % NBN) * BN;

    const int wm = (w & 3) * 64;    // 8 waves = 4m x 2n; wave tile 64x64
    const int wn = (w >> 2) * 64;

    // ---- A staging: 4 x 16B DMA per thread; linear LDS dest, pre-swizzled source ----
    // LDS slot (row, c) holds global chunk c ^ (row & 7).
    const _Float16* ga[4];
    _Float16* la[4];
    #pragma unroll
    for (int i = 0; i < 4; ++i) {
        const int idx = tid + i * 512;          // 0..2047
        const int row = idx >> 3;               // 0..255
        const int c   = idx & 7;
        ga[i] = xh + (size_t)(m0 + row) * K_DIM + ((c ^ (row & 7)) * 8);
        la[i] = lds_a + idx * 8;
    }

    // ---- B staging: thread = (col nb, dword kp); 1 dword -> 2 swizzled 16B chunks ----
    const int nb = tid >> 2;                    // 0..127
    const int kp = tid & 3;                     // packed dword within slab
    const int* pwp = pw + (size_t)kp * N_DIM + n0 + nb;
    const float* scp = scales + n0 + nb;
    const int s7 = nb & 7;
    const int cA = (kp * 2 + 0) ^ s7;           // swizzled chunk slots
    const int cB = (kp * 2 + 1) ^ s7;
    _Float16* bl = lds_b + nb * BK;

    floatx16 acc[2][2];
    #pragma unroll
    for (int i = 0; i < 2; ++i)
        #pragma unroll
        for (int j = 0; j < 2; ++j)
            acc[i][j] = (floatx16)(0.f);

    const int l31 = lane & 31;                  // A row / B col / C col within 32-tile
    const int h5  = lane >> 5;                  // k-octet selector
    const int r7  = l31 & 7;

    const int aoff0 = (wm +  0 + l31) * BK;
    const int aoff1 = (wm + 32 + l31) * BK;
    const int boff0 = (wn +  0 + l31) * BK;
    const int boff1 = (wn + 32 + l31) * BK;

    // slab-0 B operands
    uint32_t pv = (uint32_t)pwp[0];
    float    sv = scp[0];

    for (int t = 0; t < NSLAB; ++t) {
        // A: async DMA global->LDS (starts earliest; latency covered until sync1)
        #pragma unroll
        for (int i = 0; i < 4; ++i)
            async_lds16(ga[i] + t * BK, la[i]);

        // prefetch next slab's B operands (consumed next iteration)
        uint32_t pvN = pv; float svN = sv;
        if (t + 1 < NSLAB) {
            pvN = (uint32_t)pwp[(size_t)(t + 1) * 4 * N_DIM];
            svN = scp[(size_t)((t + 1) >> 1) * N_DIM];
        }

        // B: unpack 16 ternary codes -> fp16 {-s, 0, +s} (exact), swizzled ds_write
        {
            _Float16 sh = (_Float16)sv;        // lossless (value is fp16)
            uint32_t sbits = (uint32_t)__builtin_bit_cast(unsigned short, sh);
            // template bytes: [0]=lo(s) [1]=hi(+s) [2]=0x00 [3]=hi(-s); s > 0
            uint32_t tmpl = sbits | (((sbits >> 8) ^ 0x80u) << 24);
            uint32_t q[8];
            #pragma unroll
            for (int j = 0; j < 8; ++j) {
                uint32_t t4 = (pv >> (4 * j)) & 0xFu;            // c0 @bits1:0, c1 @bits3:2
                uint32_t sp = (t4 | (t4 << 14)) & 0x00030003u;   // c0 @byte0, c1 @byte2
                uint32_t sel = ((sp & 0x00010001u) << 1) | ((0x00030003u - sp) << 8);
                q[j] = __builtin_amdgcn_perm(tmpl, tmpl, sel);
            }
            *(uint4*)(bl + cA * 8) = make_uint4(q[0], q[1], q[2], q[3]);
            *(uint4*)(bl + cB * 8) = make_uint4(q[4], q[5], q[6], q[7]);
        }

        __syncthreads();   // drains vmcnt (A DMA + prefetch) + lgkm (B writes)

        #pragma unroll
        for (int ks = 0; ks < 4; ++ks) {
            const int ck = ((ks * 2 + h5) ^ r7) * 8;
            half8 af0 = *(const half8*)&lds_a[aoff0 + ck];
            half8 af1 = *(const half8*)&lds_a[aoff1 + ck];
            half8 bf0 = *(const half8*)&lds_b[boff0 + ck];
            half8 bf1 = *(const half8*)&lds_b[boff1 + ck];
            acc[0][0] = __builtin_amdgcn_mfma_f32_32x32x16_f16(af0, bf0, acc[0][0], 0, 0, 0);
            acc[0][1] = __builtin_amdgcn_mfma_f32_32x32x16_f16(af0, bf1, acc[0][1], 0, 0, 0);
            acc[1][0] = __builtin_amdgcn_mfma_f32_32x32x16_f16(af1, bf0, acc[1][0], 0, 0, 0);
            acc[1][1] = __builtin_amdgcn_mfma_f32_32x32x16_f16(af1, bf1, acc[1][1], 0, 0, 0);
        }

        __syncthreads();   // protect LDS before next slab overwrites
        pv = pvN; sv = svN;
    }

    // ---- epilogue: fp32 acc + fp32 bias, stored unrounded (validated numerics) ----
    // C/D layout (32x32, guide m74/m101): col = lane&31, row = (reg&3)+8*(reg>>2)+4*(lane>>5)
    float bvE[2];
    #pragma unroll
    for (int nt = 0; nt < 2; ++nt) bvE[nt] = bias[n0 + wn + nt * 32 + l31];

    #pragma unroll
    for (int mt = 0; mt < 2; ++mt) {
        #pragma unroll
        for (int nt = 0; nt < 2; ++nt) {
            const int col = n0 + wn + nt * 32 + l31;
            const floatx16 a = acc[mt][nt];
            #pragma unroll
            for (int reg = 0; reg < 16; ++reg) {
                const int row = m0 + wm + mt * 32 + (reg & 3) + 8 * (reg >> 2) + 4 * h5;
                out[(size_t)row * N_DIM + col] = a[reg] + bvE[nt];
            }
        }
    }
}

// ---------------- fallback: round-0 validated kernel (used if ws too small) ------------
__global__ __launch_bounds__(256, 2) void ternary_gemm(
    const float* __restrict__ x,
    const int*   __restrict__ pw,
    const float* __restrict__ scales,
    const float* __restrict__ bias,
    float*       __restrict__ out)
{
    __shared__ __align__(16) _Float16 lds_a[FBM * FASTRIDE];
    __shared__ __align__(16) _Float16 lds_b[FBM * FBSTRIDE];

    const int tid  = threadIdx.x;
    const int lane = tid & 63;
    const int wave = tid >> 6;

    const int n0 = blockIdx.x * FBM;
    const int m0 = blockIdx.y * FBM;

    const int wm = (wave & 1) * 64;
    const int wn = (wave >> 1) * 64;

    const int nb  = tid & 127;
    const int kpi = tid >> 7;
    const int*   pwp = pw + (size_t)kpi * N_DIM + n0 + nb;
    const float* scp = scales + n0 + nb;
    _Float16* bl = lds_b + nb * FBSTRIDE + kpi * 16;

    floatx4 acc[4][4];
    #pragma unroll
    for (int i = 0; i < 4; ++i)
        #pragma unroll
        for (int j = 0; j < 4; ++j)
            acc[i][j] = floatx4{0.f, 0.f, 0.f, 0.f};

    const int lr = lane & 15;
    const int qk = (lane >> 4) * 8;

    for (int slab = 0; slab < K_DIM / FBK; ++slab) {
        const int k0 = slab * FBK;

        #pragma unroll
        for (int i = 0; i < 4; ++i) {
            const int idx = tid + i * 256;
            const int row = idx >> 3;
            const int kq  = (idx & 7) * 4;
            float4 v4 = *(const float4*)(x + (size_t)(m0 + row) * K_DIM + k0 + kq);
            half2v h0; h0[0] = (_Float16)v4.x; h0[1] = (_Float16)v4.y;
            half2v h1; h1[0] = (_Float16)v4.z; h1[1] = (_Float16)v4.w;
            *(uint2*)(lds_a + row * FASTRIDE + kq) =
                make_uint2(__builtin_bit_cast(uint32_t, h0),
                           __builtin_bit_cast(uint32_t, h1));
        }

        uint32_t v  = (uint32_t)pwp[(size_t)slab * 2 * N_DIM];
        _Float16 sh = (_Float16)scp[(size_t)(slab >> 2) * N_DIM];
        uint32_t sbits = (uint32_t)__builtin_bit_cast(unsigned short, sh);
        uint32_t tmpl = sbits | (((sbits >> 8) ^ 0x80u) << 24);

        uint32_t q[8];
        #pragma unroll
        for (int j = 0; j < 8; ++j) {
            uint32_t t4 = (v >> (4 * j)) & 0xFu;
            uint32_t sp = (t4 | (t4 << 14)) & 0x00030003u;
            uint32_t sel = ((sp & 0x00010001u) << 1) | ((0x00030003u - sp) << 8);
            q[j] = __builtin_amdgcn_perm(tmpl, tmpl, sel);
        }
        *(uint4*)(bl)     = make_uint4(q[0], q[1], q[2], q[3]);
        *(uint4*)(bl + 8) = make_uint4(q[4], q[5], q[6], q[7]);

        __syncthreads();

        half8 af[4], bfr[4];
        #pragma unroll
        for (int t = 0; t < 4; ++t) {
            af[t]  = *(const half8*)&lds_a[(wm + t * 16 + lr) * FASTRIDE + qk];
            bfr[t] = *(const half8*)&lds_b[(wn + t * 16 + lr) * FBSTRIDE + qk];
        }
        #pragma unroll
        for (int mt = 0; mt < 4; ++mt)
            #pragma unroll
            for (int nt = 0; nt < 4; ++nt)
                acc[mt][nt] = __builtin_amdgcn_mfma_f32_16x16x32_f16(
                    af[mt], bfr[nt], acc[mt][nt], 0, 0, 0);

        __syncthreads();
    }

    float bv[4];
    #pragma unroll
    for (int nt = 0; nt < 4; ++nt) bv[nt] = bias[n0 + wn + nt * 16 + lr];

    const int rbase = (lane >> 4) * 4;
    #pragma unroll
    for (int mt = 0; mt < 4; ++mt) {
        #pragma unroll
        for (int nt = 0; nt < 4; ++nt) {
            const int col = n0 + wn + nt * 16 + lr;
            float* op = out + (size_t)(m0 + wm + mt * 16 + rbase) * N_DIM + col;
            floatx4 a = acc[mt][nt];
            #pragma unroll
            for (int r = 0; r < 4; ++r)
                op[(size_t)r * N_DIM] = a[r] + bv[nt];
        }
    }
}

extern "C" void kernel_launch(void* const* d_in, const int* in_sizes, int n_in,
                              void* d_out, int out_size, void* d_ws, size_t ws_size,
                              hipStream_t stream) {
    const float* x  = (const float*)d_in[0];
    const int*   pw = (const int*)d_in[1];
    const float* sc = (const float*)d_in[2];
    const float* bs = (const float*)d_in[3];
    float* out = (float*)d_out;

    if (d_ws != nullptr && ws_size >= WS_NEEDED) {
        _Float16* xh = (_Float16*)d_ws;
        cvt_a<<<dim3((unsigned)((size_t)M_DIM * K_DIM / (256 * 8))), 256, 0, stream>>>(x, xh);
        ternary_gemm_w3<<<dim3(NWG), 512, 0, stream>>>(xh, pw, sc, bs, out);
    } else {
        ternary_gemm<<<dim3(N_DIM / FBM, M_DIM / FBM), 256, 0, stream>>>(x, pw, sc, bs, out);
    }
}

// Round 6
// 1055.777 us; speedup vs baseline: 1.3389x; 1.1202x over previous
//
#include <hip/hip_runtime.h>
#include <stdint.h>

#define K_DIM 4096
#define N_DIM 11008
#define M_DIM 8192
#define BM 256
#define BN 128
#define BK 64
#define NSLAB (K_DIM / BK)   // 64
#define NBN (N_DIM / BN)     // 86
#define NBM (M_DIM / BM)     // 32
#define NWG (NBN * NBM)      // 2752, % 8 == 0
#define ABUF (BM * BK)       // 16384 halves = 32 KiB per A buffer

// fallback (round-0 validated) kernel params
#define FBM 128
#define FBK 32
#define FASTRIDE 32
#define FBSTRIDE 40

typedef _Float16 half8   __attribute__((ext_vector_type(8)));
typedef _Float16 half2v  __attribute__((ext_vector_type(2)));
typedef float    floatx4 __attribute__((ext_vector_type(4)));

#define WS_NEEDED ((size_t)M_DIM * K_DIM * 2)   // 64 MiB: fp16 copy of x

__device__ __forceinline__ void async_lds16(const void* g, void* l) {
    __builtin_amdgcn_global_load_lds(
        (const __attribute__((address_space(1))) uint32_t*)g,
        (__attribute__((address_space(3))) uint32_t*)l, 16, 0, 0);
}

// ---------------- prepass: x fp32 -> fp16 (lossless; values are fp16-representable) ----
__global__ __launch_bounds__(256) void cvt_a(const float* __restrict__ x,
                                             _Float16* __restrict__ xh) {
    const size_t i = ((size_t)blockIdx.x * 256 + threadIdx.x) * 8;
    const float4 a = *(const float4*)(x + i);
    const float4 b = *(const float4*)(x + i + 4);
    half8 h;
    h[0] = (_Float16)a.x; h[1] = (_Float16)a.y; h[2] = (_Float16)a.z; h[3] = (_Float16)a.w;
    h[4] = (_Float16)b.x; h[5] = (_Float16)b.y; h[6] = (_Float16)b.z; h[7] = (_Float16)b.w;
    *(half8*)(xh + i) = h;
}

// ---------------- main GEMM: r2 structure + A double-buffer with counted vmcnt --------
// LDS = 2x32K (A dbuf) + 16K (B, XOR-swizzled) = 80 KiB -> 2 blocks/CU at (512,4).
// Loop: issue DMA(t+1) -> other A buf FIRST, pv(t+2) prefetch, B(t) dequant+write,
// then vmcnt(6) (drains DMA(t) ONLY; DMA(t+1)+pv stay in flight), lgkm(0), s_barrier,
// MFMA (16x16x32, r2's exact 4x4 pattern, setprio-wrapped), lgkm(0), s_barrier.
// DMA(t) latency is covered by the whole MFMA phase of t-1 instead of ~40 VALU ops.
__global__ __launch_bounds__(512, 4) void ternary_gemm_p2(
    const _Float16* __restrict__ xh,   // (M, K) fp16
    const int*   __restrict__ pw,      // (K/16, N) packed 2-bit codes
    const float* __restrict__ scales,  // (K/128, N) fp32 holding fp16 values
    const float* __restrict__ bias,    // (N,) fp32 holding fp16 values
    float*       __restrict__ out)     // (M, N) fp32
{
    __shared__ __align__(16) _Float16 lds_a[2 * ABUF];  // 64 KiB, linear dest (DMA)
    __shared__ __align__(16) _Float16 lds_b[BN * BK];   // 16 KiB, XOR-swizzled content

    const int tid  = threadIdx.x;
    const int lane = tid & 63;
    const int w    = tid >> 6;

    // XCD-aware bijective swizzle; m-panel-major within an XCD chunk (FETCH 456->276MB, r5)
    const int bid = blockIdx.x;
    const int swz = (bid & 7) * (NWG / 8) + (bid >> 3);
    const int m0 = (swz / NBN) * BM;
    const int n0 = (swz % NBN) * BN;

    const int band = (w & 3) * 64;    // 8 waves = 4m x 2n; wave tile 64x64
    const int wn   = (w >> 2) * 64;

    // ---- A staging: 4 x 16B DMA per thread; linear LDS dest, pre-swizzled source ----
    // LDS slot (row, c) holds global chunk c ^ (row & 7).
    const _Float16* ga[4];
    int laOff[4];
    #pragma unroll
    for (int i = 0; i < 4; ++i) {
        const int idx = tid + i * 512;          // 0..2047
        const int row = idx >> 3;               // 0..255
        const int c   = idx & 7;
        ga[i]    = xh + (size_t)(m0 + row) * K_DIM + ((c ^ (row & 7)) * 8);
        laOff[i] = idx * 8;
    }

    // ---- B staging: thread = (col nb, dword kp); 1 dword -> 2 swizzled 16B chunks ----
    const int nb = tid >> 2;                    // 0..127
    const int kp = tid & 3;                     // packed dword within slab
    const int* pwp = pw + (size_t)kp * N_DIM + n0 + nb;
    const float* scp = scales + n0 + nb;
    const int s7 = nb & 7;
    const int cA = (kp * 2 + 0) ^ s7;           // swizzled chunk slots
    const int cB = (kp * 2 + 1) ^ s7;
    _Float16* bl = lds_b + nb * BK;

    floatx4 acc[4][4];
    #pragma unroll
    for (int i = 0; i < 4; ++i)
        #pragma unroll
        for (int j = 0; j < 4; ++j)
            acc[i][j] = floatx4{0.f, 0.f, 0.f, 0.f};

    const int lr = lane & 15;                   // row (A) / col (B,C) within 16-tile
    const int g  = lane >> 4;                   // k-quad
    const int x7 = lr & 7;

    int aoff[4], boff[4];
    #pragma unroll
    for (int t = 0; t < 4; ++t) {
        aoff[t] = (band + t * 16 + lr) * BK;
        boff[t] = (wn   + t * 16 + lr) * BK;
    }

    auto stage_a = [&](int t, int buf) {
        #pragma unroll
        for (int i = 0; i < 4; ++i)
            async_lds16(ga[i] + t * BK, lds_a + buf * ABUF + laOff[i]);
    };
    // exact ternary dequant: 16 codes -> fp16 {-s, 0, +s} via v_perm byte templates
    auto stage_b = [&](uint32_t v, float scf) {
        _Float16 sh = (_Float16)scf;            // lossless (value is fp16)
        uint32_t sbits = (uint32_t)__builtin_bit_cast(unsigned short, sh);
        // template bytes: [0]=lo(s) [1]=hi(+s) [2]=0x00 [3]=hi(-s); s > 0
        uint32_t tmpl = sbits | (((sbits >> 8) ^ 0x80u) << 24);
        uint32_t q[8];
        #pragma unroll
        for (int j = 0; j < 8; ++j) {
            uint32_t t4 = (v >> (4 * j)) & 0xFu;             // c0 @bits1:0, c1 @bits3:2
            uint32_t sp = (t4 | (t4 << 14)) & 0x00030003u;   // c0 @byte0, c1 @byte2
            uint32_t sel = ((sp & 0x00010001u) << 1) | ((0x00030003u - sp) << 8);
            q[j] = __builtin_amdgcn_perm(tmpl, tmpl, sel);
        }
        *(uint4*)(bl + cA * 8) = make_uint4(q[0], q[1], q[2], q[3]);
        *(uint4*)(bl + cB * 8) = make_uint4(q[4], q[5], q[6], q[7]);
    };

    // ---- prologue: DMA slab 0 into buf0; pv(0), pv(1) loaded (blocking is fine) ----
    stage_a(0, 0);
    uint32_t pv0 = (uint32_t)pwp[0];
    float    sv0 = scp[0];
    uint32_t pv1 = (uint32_t)pwp[(size_t)4 * N_DIM];
    float    sv1 = scp[0];                      // group of slab 1 == 0

    for (int t = 0; t < NSLAB; ++t) {
        const int cur = t & 1;

        // (a) issue next slab's A-DMA into the other buffer (in flight through MFMA(t))
        if (t + 1 < NSLAB) stage_a(t + 1, cur ^ 1);
        // (b) prefetch slab t+2's packed dword + scale
        uint32_t pv2 = 0; float sv2 = 0.f;
        if (t + 2 < NSLAB) {
            pv2 = (uint32_t)pwp[(size_t)(t + 2) * 4 * N_DIM];
            sv2 = scp[(size_t)((t + 2) >> 1) * N_DIM];
        }
        // (c) B(t): dequant + swizzled ds_write (lds_b free since g-barrier(t-1))
        stage_b(pv0, sv0);

        // (d) drain DMA(t) only; DMA(t+1) [4] + pv2 [2] remain outstanding (T4)
        if (t + 2 < NSLAB)      asm volatile("s_waitcnt vmcnt(6)" ::: "memory");
        else if (t + 1 < NSLAB) asm volatile("s_waitcnt vmcnt(4)" ::: "memory");
        else                    asm volatile("s_waitcnt vmcnt(0)" ::: "memory");
        asm volatile("s_waitcnt lgkmcnt(0)" ::: "memory");   // my B writes landed
        __builtin_amdgcn_sched_barrier(0);
        __builtin_amdgcn_s_barrier();            // buf[cur] + lds_b published

        // (f) MFMA on buf[cur] + lds_b  (r2's exact fragment pattern)
        const _Float16* Ab = lds_a + cur * ABUF;
        __builtin_amdgcn_s_setprio(1);
        #pragma unroll
        for (int h = 0; h < 2; ++h) {
            const int co = ((h * 4 + g) ^ x7) * 8;
            half8 af[4], bfr[4];
            #pragma unroll
            for (int tt = 0; tt < 4; ++tt) {
                af[tt]  = *(const half8*)&Ab[aoff[tt] + co];
                bfr[tt] = *(const half8*)&lds_b[boff[tt] + co];
            }
            #pragma unroll
            for (int mt = 0; mt < 4; ++mt)
                #pragma unroll
                for (int nt = 0; nt < 4; ++nt)
                    acc[mt][nt] = __builtin_amdgcn_mfma_f32_16x16x32_f16(
                        af[mt], bfr[nt], acc[mt][nt], 0, 0, 0);
        }
        __builtin_amdgcn_s_setprio(0);

        // (g) my ds reads complete -> safe for next iter's B overwrite after barrier
        asm volatile("s_waitcnt lgkmcnt(0)" ::: "memory");
        __builtin_amdgcn_sched_barrier(0);
        __builtin_amdgcn_s_barrier();

        pv0 = pv1; sv0 = sv1; pv1 = pv2; sv1 = sv2;
    }

    // ---- epilogue: fp32 acc + fp32 bias, stored unrounded (validated numerics) ----
    float bv[4];
    #pragma unroll
    for (int nt = 0; nt < 4; ++nt) bv[nt] = bias[n0 + wn + nt * 16 + lr];

    const int rbase = g * 4;          // C layout: row = (lane>>4)*4 + reg
    #pragma unroll
    for (int mt = 0; mt < 4; ++mt) {
        #pragma unroll
        for (int nt = 0; nt < 4; ++nt) {
            const int col = n0 + wn + nt * 16 + lr;
            float* op = out + (size_t)(m0 + band + mt * 16 + rbase) * N_DIM + col;
            floatx4 a = acc[mt][nt];
            #pragma unroll
            for (int r = 0; r < 4; ++r)
                op[(size_t)r * N_DIM] = a[r] + bv[nt];
        }
    }
}

// ---------------- fallback: round-0 validated kernel (used if ws too small) ------------
__global__ __launch_bounds__(256, 2) void ternary_gemm(
    const float* __restrict__ x,
    const int*   __restrict__ pw,
    const float* __restrict__ scales,
    const float* __restrict__ bias,
    float*       __restrict__ out)
{
    __shared__ __align__(16) _Float16 lds_a[FBM * FASTRIDE];
    __shared__ __align__(16) _Float16 lds_b[FBM * FBSTRIDE];

    const int tid  = threadIdx.x;
    const int lane = tid & 63;
    const int wave = tid >> 6;

    const int n0 = blockIdx.x * FBM;
    const int m0 = blockIdx.y * FBM;

    const int wm = (wave & 1) * 64;
    const int wn = (wave >> 1) * 64;

    const int nb  = tid & 127;
    const int kpi = tid >> 7;
    const int*   pwp = pw + (size_t)kpi * N_DIM + n0 + nb;
    const float* scp = scales + n0 + nb;
    _Float16* bl = lds_b + nb * FBSTRIDE + kpi * 16;

    floatx4 acc[4][4];
    #pragma unroll
    for (int i = 0; i < 4; ++i)
        #pragma unroll
        for (int j = 0; j < 4; ++j)
            acc[i][j] = floatx4{0.f, 0.f, 0.f, 0.f};

    const int lr = lane & 15;
    const int qk = (lane >> 4) * 8;

    for (int slab = 0; slab < K_DIM / FBK; ++slab) {
        const int k0 = slab * FBK;

        #pragma unroll
        for (int i = 0; i < 4; ++i) {
            const int idx = tid + i * 256;
            const int row = idx >> 3;
            const int kq  = (idx & 7) * 4;
            float4 v4 = *(const float4*)(x + (size_t)(m0 + row) * K_DIM + k0 + kq);
            half2v h0; h0[0] = (_Float16)v4.x; h0[1] = (_Float16)v4.y;
            half2v h1; h1[0] = (_Float16)v4.z; h1[1] = (_Float16)v4.w;
            *(uint2*)(lds_a + row * FASTRIDE + kq) =
                make_uint2(__builtin_bit_cast(uint32_t, h0),
                           __builtin_bit_cast(uint32_t, h1));
        }

        uint32_t v  = (uint32_t)pwp[(size_t)slab * 2 * N_DIM];
        _Float16 sh = (_Float16)scp[(size_t)(slab >> 2) * N_DIM];
        uint32_t sbits = (uint32_t)__builtin_bit_cast(unsigned short, sh);
        uint32_t tmpl = sbits | (((sbits >> 8) ^ 0x80u) << 24);

        uint32_t q[8];
        #pragma unroll
        for (int j = 0; j < 8; ++j) {
            uint32_t t4 = (v >> (4 * j)) & 0xFu;
            uint32_t sp = (t4 | (t4 << 14)) & 0x00030003u;
            uint32_t sel = ((sp & 0x00010001u) << 1) | ((0x00030003u - sp) << 8);
            q[j] = __builtin_amdgcn_perm(tmpl, tmpl, sel);
        }
        *(uint4*)(bl)     = make_uint4(q[0], q[1], q[2], q[3]);
        *(uint4*)(bl + 8) = make_uint4(q[4], q[5], q[6], q[7]);

        __syncthreads();

        half8 af[4], bfr[4];
        #pragma unroll
        for (int t = 0; t < 4; ++t) {
            af[t]  = *(const half8*)&lds_a[(wm + t * 16 + lr) * FASTRIDE + qk];
            bfr[t] = *(const half8*)&lds_b[(wn + t * 16 + lr) * FBSTRIDE + qk];
        }
        #pragma unroll
        for (int mt = 0; mt < 4; ++mt)
            #pragma unroll
            for (int nt = 0; nt < 4; ++nt)
                acc[mt][nt] = __builtin_amdgcn_mfma_f32_16x16x32_f16(
                    af[mt], bfr[nt], acc[mt][nt], 0, 0, 0);

        __syncthreads();
    }

    float bv[4];
    #pragma unroll
    for (int nt = 0; nt < 4; ++nt) bv[nt] = bias[n0 + wn + nt * 16 + lr];

    const int rbase = (lane >> 4) * 4;
    #pragma unroll
    for (int mt = 0; mt < 4; ++mt) {
        #pragma unroll
        for (int nt = 0; nt < 4; ++nt) {
            const int col = n0 + wn + nt * 16 + lr;
            float* op = out + (size_t)(m0 + wm + mt * 16 + rbase) * N_DIM + col;
            floatx4 a = acc[mt][nt];
            #pragma unroll
            for (int r = 0; r < 4; ++r)
                op[(size_t)r * N_DIM] = a[r] + bv[nt];
        }
    }
}

extern "C" void kernel_launch(void* const* d_in, const int* in_sizes, int n_in,
                              void* d_out, int out_size, void* d_ws, size_t ws_size,
                              hipStream_t stream) {
    const float* x  = (const float*)d_in[0];
    const int*   pw = (const int*)d_in[1];
    const float* sc = (const float*)d_in[2];
    const float* bs = (const float*)d_in[3];
    float* out = (float*)d_out;

    if (d_ws != nullptr && ws_size >= WS_NEEDED) {
        _Float16* xh = (_Float16*)d_ws;
        cvt_a<<<dim3((unsigned)((size_t)M_DIM * K_DIM / (256 * 8))), 256, 0, stream>>>(x, xh);
        ternary_gemm_p2<<<dim3(NWG), 512, 0, stream>>>(xh, pw, sc, bs, out);
    } else {
        ternary_gemm<<<dim3(N_DIM / FBM, M_DIM / FBM), 256, 0, stream>>>(x, pw, sc, bs, out);
    }
}